// Round 3
// baseline (29.066 us; speedup 1.0000x reference)
//
#include <hip/hip_runtime.h>
#include <hip/hip_bf16.h>

#define DD 128
#define NTRK 1024
#define NDET 1024

typedef __attribute__((ext_vector_type(8))) short short8;
typedef __attribute__((ext_vector_type(4))) float f32x4;

static __device__ __forceinline__ short bfb(float x) {
    __hip_bfloat16 h = __float2bfloat16(x);
    return __builtin_bit_cast(short, h);
}
static __device__ __forceinline__ float bff(short s) {
    unsigned int u = ((unsigned int)(unsigned short)s) << 16;
    return __builtin_bit_cast(float, u);
}
static __device__ __forceinline__ short8 packbf8(const float* f) {
    short8 r;
    #pragma unroll
    for (int j = 0; j < 8; ++j) r[j] = bfb(f[j]);
    return r;
}

// ---------------------------------------------------------------------------
// One fused kernel. Block = 512 thr (8 waves), output tile 32(n) x 64(m).
// Grid = (1024/64 mchunks, 1024/32 ntiles) = (16, 32) = 512 blocks
//   -> 2 blocks/CU, 4 waves/SIMD.
// Phase 1: obj[32][128] = bf16(det @ Wd + bd) via MFMA, wave w -> d-cols
//          [16w,16w+16). Stored in XOR-swizzled LDS (conflict-free b128 read).
//          blockIdx.x==0 blocks also emit trk_nb = det @ Wt + bt via 3-term
//          bf16 hi/lo split MFMA (error ~2e-5). Waves 0-1 reduce wsum/bsum.
// Phase 2: d2t via SWAPPED mfma(trk, obj) -> D[m][n]: lane owns n=lr fixed,
//          m = base+lq*4+{0..3} CONSECUTIVE -> rel epilogue = 3 aligned
//          float4 loads per lane. Result transposed through padded LDS for
//          coalesced float4 global stores.
// ---------------------------------------------------------------------------
__global__ __launch_bounds__(512, 4) void fused_kernel(
    const float* __restrict__ det, const float* __restrict__ trk,
    const float* __restrict__ rel,
    const float* __restrict__ Wd, const float* __restrict__ bd,
    const float* __restrict__ Wt, const float* __restrict__ bt,
    const float* __restrict__ Wr, const float* __restrict__ br,
    float* __restrict__ out, float* __restrict__ trk_nb)
{
    const int t  = threadIdx.x;
    const int w  = t >> 6;          // wave 0..7
    const int l  = t & 63;
    const int lq = l >> 4;          // 0..3
    const int lr = l & 15;
    const int m0 = blockIdx.x * 64;
    const int n0 = blockIdx.y * 32;

    __shared__ __align__(16) char  objs[32 * 256];   // [32][128] bf16, swizzled
    __shared__ __align__(16) float outs[32][68];     // padded out tile
    __shared__ float part[2][4];

    // ---- wsum partials (waves 0,1) ----
    if (t < 128) {
        float v0 = Wr[t], v1 = Wr[128 + t], v2 = Wr[256 + t], v3 = br[t];
        #pragma unroll
        for (int off = 32; off; off >>= 1) {
            v0 += __shfl_down(v0, off);
            v1 += __shfl_down(v1, off);
            v2 += __shfl_down(v2, off);
            v3 += __shfl_down(v3, off);
        }
        if (l == 0) { part[w][0] = v0; part[w][1] = v1; part[w][2] = v2; part[w][3] = v3; }
    }

    // ---- Phase 1: obj tile via MFMA ----
    short8 ah[2][4];                 // det bf16 A-frags [nsub][ks]
    #pragma unroll
    for (int ns = 0; ns < 2; ++ns) {
        #pragma unroll
        for (int ks = 0; ks < 4; ++ks) {
            const float* p = det + (size_t)(n0 + ns * 16 + lr) * DD + ks * 32 + lq * 8;
            float df[8];
            *reinterpret_cast<float4*>(&df[0]) = *reinterpret_cast<const float4*>(p);
            *reinterpret_cast<float4*>(&df[4]) = *reinterpret_cast<const float4*>(p + 4);
            ah[ns][ks] = packbf8(df);
        }
    }

    f32x4 accd0 = {0.f, 0.f, 0.f, 0.f}, accd1 = {0.f, 0.f, 0.f, 0.f};
    #pragma unroll
    for (int ks = 0; ks < 4; ++ks) {
        float wv[8];
        #pragma unroll
        for (int j = 0; j < 8; ++j)
            wv[j] = Wd[(size_t)(ks * 32 + lq * 8 + j) * DD + w * 16 + lr];
        const short8 b = packbf8(wv);
        accd0 = __builtin_amdgcn_mfma_f32_16x16x32_bf16(ah[0][ks], b, accd0, 0, 0, 0);
        accd1 = __builtin_amdgcn_mfma_f32_16x16x32_bf16(ah[1][ks], b, accd1, 0, 0, 0);
    }

    const float bdv = bd[w * 16 + lr];
    #pragma unroll
    for (int r = 0; r < 4; ++r) {
        // nsub 0
        int n = lq * 4 + r;
        int off = (n * 256 + (w * 16 + lr) * 2) ^ ((n & 7) << 4);
        *reinterpret_cast<short*>(&objs[off]) = bfb(accd0[r] + bdv);
        // nsub 1
        n = 16 + lq * 4 + r;
        off = (n * 256 + (w * 16 + lr) * 2) ^ ((n & 7) << 4);
        *reinterpret_cast<short*>(&objs[off]) = bfb(accd1[r] + bdv);
    }

    // ---- trk_nb (exact-ish, 3-term split) on mchunk==0 blocks ----
    if (blockIdx.x == 0) {
        #pragma unroll
        for (int ns = 0; ns < 2; ++ns) {
            short8 al[4];
            #pragma unroll
            for (int ks = 0; ks < 4; ++ks) {
                const float* p = det + (size_t)(n0 + ns * 16 + lr) * DD + ks * 32 + lq * 8;
                float df[8];
                *reinterpret_cast<float4*>(&df[0]) = *reinterpret_cast<const float4*>(p);
                *reinterpret_cast<float4*>(&df[4]) = *reinterpret_cast<const float4*>(p + 4);
                short8 lo;
                #pragma unroll
                for (int j = 0; j < 8; ++j) lo[j] = bfb(df[j] - bff(ah[ns][ks][j]));
                al[ks] = lo;
            }
            f32x4 acct = {0.f, 0.f, 0.f, 0.f};
            #pragma unroll
            for (int ks = 0; ks < 4; ++ks) {
                float wv[8];
                #pragma unroll
                for (int j = 0; j < 8; ++j)
                    wv[j] = Wt[(size_t)(ks * 32 + lq * 8 + j) * DD + w * 16 + lr];
                short8 bh, bl;
                #pragma unroll
                for (int j = 0; j < 8; ++j) {
                    bh[j] = bfb(wv[j]);
                    bl[j] = bfb(wv[j] - bff(bh[j]));
                }
                acct = __builtin_amdgcn_mfma_f32_16x16x32_bf16(ah[ns][ks], bh, acct, 0, 0, 0);
                acct = __builtin_amdgcn_mfma_f32_16x16x32_bf16(ah[ns][ks], bl, acct, 0, 0, 0);
                acct = __builtin_amdgcn_mfma_f32_16x16x32_bf16(al[ks],     bh, acct, 0, 0, 0);
            }
            const float btv = bt[w * 16 + lr];
            #pragma unroll
            for (int r = 0; r < 4; ++r)
                trk_nb[(size_t)(n0 + ns * 16 + lq * 4 + r) * DD + w * 16 + lr] = acct[r] + btv;
        }
    }

    __syncthreads();

    // ---- Phase 2: d2t via swapped mfma(trk, obj) ----
    const float inv = 0.08838834764831845f;   // 1/sqrt(128)
    const float w0 = (part[0][0] + part[1][0]) * inv;
    const float w1 = (part[0][1] + part[1][1]) * inv;
    const float w2 = (part[0][2] + part[1][2]) * inv;
    const float bs = (part[0][3] + part[1][3]) * inv;

    const int ns = w >> 2;          // 0..1
    const int ms = w & 3;           // 0..3

    short8 bo[4];                   // obj B-frags (lane lr -> n-col)
    {
        const int n = ns * 16 + lr;
        #pragma unroll
        for (int ks = 0; ks < 4; ++ks) {
            const int off = (n * 256 + ks * 64 + lq * 16) ^ ((n & 7) << 4);
            bo[ks] = *reinterpret_cast<const short8*>(&objs[off]);
        }
    }

    f32x4 acc = {0.f, 0.f, 0.f, 0.f};
    #pragma unroll
    for (int ks = 0; ks < 4; ++ks) {
        const float* p = trk + (size_t)(m0 + ms * 16 + lr) * DD + ks * 32 + lq * 8;
        float tf[8];
        *reinterpret_cast<float4*>(&tf[0]) = *reinterpret_cast<const float4*>(p);
        *reinterpret_cast<float4*>(&tf[4]) = *reinterpret_cast<const float4*>(p + 4);
        const short8 a = packbf8(tf);
        acc = __builtin_amdgcn_mfma_f32_16x16x32_bf16(a, bo[ks], acc, 0, 0, 0);
    }

    // epilogue: lane owns n = n0+ns*16+lr, m = m0+ms*16+lq*4+{0..3}
    {
        const int ng = n0 + ns * 16 + lr;
        const int mb = m0 + ms * 16 + lq * 4;
        const float4* rp = reinterpret_cast<const float4*>(rel + ((size_t)ng * NTRK + mb) * 3);
        const float4 v0 = rp[0], v1 = rp[1], v2 = rp[2];
        float4 res;
        res.x = fmaf(acc[0], inv, bs + v0.x * w0 + v0.y * w1 + v0.z * w2);
        res.y = fmaf(acc[1], inv, bs + v0.w * w0 + v1.x * w1 + v1.y * w2);
        res.z = fmaf(acc[2], inv, bs + v1.z * w0 + v1.w * w1 + v2.x * w2);
        res.w = fmaf(acc[3], inv, bs + v2.y * w0 + v2.z * w1 + v2.w * w2);
        *reinterpret_cast<float4*>(&outs[ns * 16 + lr][ms * 16 + lq * 4]) = res;
    }

    __syncthreads();

    // ---- coalesced store of the 32x64 tile ----
    {
        const int row = t >> 4, c = t & 15;
        const float4 vv = *reinterpret_cast<const float4*>(&outs[row][c * 4]);
        *reinterpret_cast<float4*>(&out[(size_t)(n0 + row) * NTRK + m0 + c * 4]) = vv;
    }
}

extern "C" void kernel_launch(void* const* d_in, const int* in_sizes, int n_in,
                              void* d_out, int out_size, void* d_ws, size_t ws_size,
                              hipStream_t stream) {
    const float* det = (const float*)d_in[0];
    const float* trk = (const float*)d_in[1];
    const float* rel = (const float*)d_in[2];
    const float* Wd  = (const float*)d_in[3];
    const float* bd  = (const float*)d_in[4];
    const float* Wt  = (const float*)d_in[5];
    const float* bt  = (const float*)d_in[6];
    const float* Wr  = (const float*)d_in[7];
    const float* br  = (const float*)d_in[8];

    float* out_mat = (float*)d_out;                        // [N_DET, N_TRK]
    float* out_trk = out_mat + (size_t)NDET * NTRK;        // [N_DET, D]

    fused_kernel<<<dim3(NTRK / 64, NDET / 32), 512, 0, stream>>>(
        det, trk, rel, Wd, bd, Wt, bt, Wr, br, out_mat, out_trk);
}

// Round 4
// 16.916 us; speedup vs baseline: 1.7183x; 1.7183x over previous
//
#include <hip/hip_runtime.h>
#include <hip/hip_bf16.h>

#define N_DET 1024
#define N_TRK 1024
#define DD 128
#define RR 3

typedef __attribute__((ext_vector_type(8))) short short8;
typedef __attribute__((ext_vector_type(4))) float f32x4;

static __device__ __forceinline__ short bfb(float x) {
    __hip_bfloat16 h = __float2bfloat16(x);
    return __builtin_bit_cast(short, h);
}

// ---------------------------------------------------------------------------
// Kernel A (prep): 512 blocks x 256 threads, 2 det rows per block, k-split 2
//   -> 2048 waves = 2 waves/SIMD (vs 1 in round 2) for L2-latency hiding.
//   objb    = bf16(det @ W_det + b_det)            -> ws
//   trk_nb  = det @ W_trk + b_trk (exact f32)      -> d_out tail
//   trkb    = bf16(track_embedding)                -> ws
//   wsum[r] = sum_d W_rel[r][d], bsum = sum_d b_rel[d]  (block 0)
// ---------------------------------------------------------------------------
__global__ __launch_bounds__(256) void prep_kernel(
    const float* __restrict__ det, const float* __restrict__ trk,
    const float* __restrict__ Wd, const float* __restrict__ bd,
    const float* __restrict__ Wt, const float* __restrict__ bt,
    const float* __restrict__ Wr, const float* __restrict__ br,
    __hip_bfloat16* __restrict__ objb, __hip_bfloat16* __restrict__ trkb,
    float* __restrict__ trk_nb, float* __restrict__ wsum)
{
    const int tid  = threadIdx.x;
    const int col  = tid & 127;
    const int half = tid >> 7;          // k-half: 0 -> k<64, 1 -> k>=64
    const int row0 = blockIdx.x * 2;

    __shared__ float det_s[2][DD];
    __shared__ float partd[2][DD];
    __shared__ float partt[2][DD];

    det_s[half][col] = det[row0 * DD + tid];
    __syncthreads();

    float ad0 = 0.f, ad1 = 0.f, at0 = 0.f, at1 = 0.f;
    const int kbase = half * 64;
    #pragma unroll 8
    for (int k = 0; k < 64; ++k) {
        const int kk = kbase + k;
        const float wd = Wd[kk * DD + col];
        const float wt = Wt[kk * DD + col];
        const float d0 = det_s[0][kk], d1 = det_s[1][kk];
        ad0 = fmaf(d0, wd, ad0);
        ad1 = fmaf(d1, wd, ad1);
        at0 = fmaf(d0, wt, at0);
        at1 = fmaf(d1, wt, at1);
    }

    if (half == 1) {
        partd[0][col] = ad0; partd[1][col] = ad1;
        partt[0][col] = at0; partt[1][col] = at1;
    }
    __syncthreads();

    if (half == 0) {
        const float bdv = bd[col], btv = bt[col];
        const float o0 = ad0 + partd[0][col] + bdv;
        const float o1 = ad1 + partd[1][col] + bdv;
        objb[row0 * DD + col]       = __float2bfloat16(o0);
        objb[(row0 + 1) * DD + col] = __float2bfloat16(o1);
        trk_nb[row0 * DD + col]       = at0 + partt[0][col] + btv;
        trk_nb[(row0 + 1) * DD + col] = at1 + partt[1][col] + btv;
    } else {
        // convert 2 track rows to bf16
        trkb[row0 * DD + col]       = __float2bfloat16(trk[row0 * DD + col]);
        trkb[(row0 + 1) * DD + col] = __float2bfloat16(trk[(row0 + 1) * DD + col]);
    }

    if (blockIdx.x == 0 && tid < 64) {
        float v0 = Wr[tid]          + Wr[64 + tid];
        float v1 = Wr[DD + tid]     + Wr[DD + 64 + tid];
        float v2 = Wr[2 * DD + tid] + Wr[2 * DD + 64 + tid];
        float v3 = br[tid]          + br[64 + tid];
        #pragma unroll
        for (int off = 32; off > 0; off >>= 1) {
            v0 += __shfl_down(v0, off);
            v1 += __shfl_down(v1, off);
            v2 += __shfl_down(v2, off);
            v3 += __shfl_down(v3, off);
        }
        if (tid == 0) { wsum[0] = v0; wsum[1] = v1; wsum[2] = v2; wsum[3] = v3; }
    }
}

// ---------------------------------------------------------------------------
// Kernel B (fuse): SWAPPED operands — D = mfma(trkb, objb) -> D[m][n].
// Lane l: n = n0 + (l&15) fixed, m = m0 + (l>>4)*4 + {0..3} CONSECUTIVE.
//   -> rel epilogue: 3 aligned float4 loads/lane (12 floats = rel[n][m..m+3][:])
//   -> output: 1 float4 store/lane, 64B-contiguous per n-row across lq.
// Block = 4 waves (m chunks), grid (1024/64, 1024/16) -> 4 blocks/CU,
// 4 waves/SIMD.
// ---------------------------------------------------------------------------
__global__ __launch_bounds__(256) void fuse_mfma_kernel(
    const __hip_bfloat16* __restrict__ objb,
    const __hip_bfloat16* __restrict__ trkb,
    const float* __restrict__ rel, const float* __restrict__ wsum,
    float* __restrict__ out)
{
    const int t  = threadIdx.x;
    const int w  = t >> 6;
    const int l  = t & 63;
    const int lq = l >> 4;                      // 0..3
    const int lr = l & 15;
    const int m0 = blockIdx.x * 64 + w * 16;
    const int n0 = blockIdx.y * 16;

    const float inv = 0.08838834764831845f;     // 1/sqrt(128)
    const float w0 = wsum[0] * inv, w1 = wsum[1] * inv;
    const float w2 = wsum[2] * inv, bs = wsum[3] * inv;

    // A = trkb rows (m), B = objb cols (n); both frags read 16B/lane,
    // per-wave pattern = 16 rows x 64B contiguous.
    const short8* ap = reinterpret_cast<const short8*>(trkb + (size_t)(m0 + lr) * DD + lq * 8);
    const short8* bp = reinterpret_cast<const short8*>(objb + (size_t)(n0 + lr) * DD + lq * 8);

    f32x4 acc = {0.f, 0.f, 0.f, 0.f};
    #pragma unroll
    for (int ks = 0; ks < 4; ++ks) {
        const short8 a = ap[ks * 4];            // advance K by 32
        const short8 b = bp[ks * 4];
        acc = __builtin_amdgcn_mfma_f32_16x16x32_bf16(a, b, acc, 0, 0, 0);
    }

    // epilogue: lane owns n = n0+lr, m = m0+lq*4 .. +3
    const int n  = n0 + lr;
    const int mb = m0 + lq * 4;
    const float4* rp = reinterpret_cast<const float4*>(rel + ((size_t)n * N_TRK + mb) * RR);
    const float4 v0 = rp[0], v1 = rp[1], v2 = rp[2];

    float4 res;
    res.x = fmaf(acc[0], inv, bs + v0.x * w0 + v0.y * w1 + v0.z * w2);
    res.y = fmaf(acc[1], inv, bs + v0.w * w0 + v1.x * w1 + v1.y * w2);
    res.z = fmaf(acc[2], inv, bs + v1.z * w0 + v1.w * w1 + v2.x * w2);
    res.w = fmaf(acc[3], inv, bs + v2.y * w0 + v2.z * w1 + v2.w * w2);

    *reinterpret_cast<float4*>(out + (size_t)n * N_TRK + mb) = res;
}

extern "C" void kernel_launch(void* const* d_in, const int* in_sizes, int n_in,
                              void* d_out, int out_size, void* d_ws, size_t ws_size,
                              hipStream_t stream) {
    const float* det = (const float*)d_in[0];
    const float* trk = (const float*)d_in[1];
    const float* rel = (const float*)d_in[2];
    const float* Wd  = (const float*)d_in[3];
    const float* bd  = (const float*)d_in[4];
    const float* Wt  = (const float*)d_in[5];
    const float* bt  = (const float*)d_in[6];
    const float* Wr  = (const float*)d_in[7];
    const float* br  = (const float*)d_in[8];

    float* out_mat = (float*)d_out;                        // [N_DET, N_TRK]
    float* out_trk = out_mat + (size_t)N_DET * N_TRK;      // [N_DET, D]

    __hip_bfloat16* objb = (__hip_bfloat16*)d_ws;          // [N_DET, D] bf16
    __hip_bfloat16* trkb = objb + (size_t)N_DET * DD;      // [N_TRK, D] bf16
    float* wsum = (float*)(trkb + (size_t)N_TRK * DD);     // [4]

    prep_kernel<<<N_DET / 2, 256, 0, stream>>>(
        det, trk, Wd, bd, Wt, bt, Wr, br, objb, trkb, out_trk, wsum);

    fuse_mfma_kernel<<<dim3(N_TRK / 64, N_DET / 16), 256, 0, stream>>>(
        objb, trkb, rel, wsum, out_mat);
}